// Round 3
// baseline (581.653 us; speedup 1.0000x reference)
//
#include <hip/hip_runtime.h>

typedef __attribute__((ext_vector_type(8))) short bf16x8;
typedef __attribute__((ext_vector_type(4))) float f32x4;
typedef __attribute__((ext_vector_type(16))) float f32x16;

#define NQ   4096
#define NKV  4096
#define CDIM 256
#define HEADS 8
#define DDIM 32

// f32 -> bf16 RNE
__device__ __forceinline__ unsigned short f2bf(float x){
  unsigned int u = __builtin_bit_cast(unsigned int, x);
  u = (u + 0x7FFFu + ((u >> 16) & 1u)) >> 16;
  return (unsigned short)u;
}

__device__ __forceinline__ void cvt8(const float* __restrict__ in,
                                     unsigned short* __restrict__ out, int i){
  const float4* p = (const float4*)in;
  float4 a = p[2*i], b = p[2*i+1];
  union { unsigned short u[8]; bf16x8 v; } o;
  o.u[0]=f2bf(a.x); o.u[1]=f2bf(a.y); o.u[2]=f2bf(a.z); o.u[3]=f2bf(a.w);
  o.u[4]=f2bf(b.x); o.u[5]=f2bf(b.y); o.u[6]=f2bf(b.z); o.u[7]=f2bf(b.w);
  ((bf16x8*)out)[i] = o.v;
}

// Convert activations to bf16 (same layout) and weights to bf16 transposed [N][K].
__global__ __launch_bounds__(256) void prep(
    const float* __restrict__ q, const float* __restrict__ kv,
    const float* __restrict__ wq, const float* __restrict__ wkv,
    const float* __restrict__ wout,
    unsigned short* __restrict__ qx, unsigned short* __restrict__ kvx,
    unsigned short* __restrict__ wqT, unsigned short* __restrict__ wkvT,
    unsigned short* __restrict__ woutT)
{
  int t = blockIdx.x * 256 + threadIdx.x;
  if (t < 262144){ cvt8(q, qx, t); }
  else if (t < 524288){ cvt8(kv, kvx, t - 262144); }
  else {
    int i = t - 524288;                       // 0 .. 262143
    if (i < 65536){ int n = i >> 8, k = i & 255; wqT[i] = f2bf(wq[k*256 + n]); }
    else if (i < 196608){ int j = i - 65536; int n = j >> 8, k = j & 255;
                          wkvT[j] = f2bf(wkv[k*512 + n]); }
    else { int j = i - 196608; int n = j >> 8, k = j & 255;
           woutT[j] = f2bf(wout[k*256 + n]); }
  }
}

// Fused Q + KV projection. blockIdx.y < 4 -> Q-mode (N=256); else KV-mode (N=512).
__global__ __launch_bounds__(256) void gemm_qkv(
    const unsigned short* __restrict__ qx,
    const unsigned short* __restrict__ kvx,
    const unsigned short* __restrict__ wqT,
    const unsigned short* __restrict__ wkvT,
    unsigned short* __restrict__ Qb,
    unsigned short* __restrict__ Kb,
    unsigned short* __restrict__ VTb)
{
  const int wid = threadIdx.x >> 6;
  const int lane = threadIdx.x & 63;
  const int l15 = lane & 15, g = lane >> 4;
  const int m0 = blockIdx.x * 64;
  const int mode = blockIdx.y >= 4;
  const int ny = mode ? (blockIdx.y - 4) : blockIdx.y;
  const int n0 = ny * 64 + wid * 16;
  const unsigned short* X  = mode ? kvx  : qx;
  const unsigned short* WT = mode ? wkvT : wqT;
  f32x4 acc[4] = {{0,0,0,0},{0,0,0,0},{0,0,0,0},{0,0,0,0}};
  const unsigned short* xp = X + (size_t)(m0 + l15) * CDIM + g * 8;
  const unsigned short* wp = WT + (size_t)(n0 + l15) * CDIM + g * 8;
  #pragma unroll
  for (int k0 = 0; k0 < CDIM; k0 += 32){
    bf16x8 bfr = *(const bf16x8*)(wp + k0);
    #pragma unroll
    for (int i = 0; i < 4; ++i){
      bf16x8 afr = *(const bf16x8*)(xp + (size_t)i*16*CDIM + k0);
      acc[i] = __builtin_amdgcn_mfma_f32_16x16x32_bf16(afr, bfr, acc[i], 0, 0, 0);
    }
  }
  #pragma unroll
  for (int i = 0; i < 4; ++i){
    #pragma unroll
    for (int r = 0; r < 4; ++r){
      int m = m0 + i*16 + g*4 + r;
      int n = n0 + l15;
      float v = acc[i][r];
      int b = m >> 12, pos = m & 4095;
      if (!mode){
        int h = n >> 5, d = n & 31;
        // scale = D^-0.5 * log2(e) folded into Q
        Qb[((size_t)(b*HEADS + h)*NQ + pos)*DDIM + d] = f2bf(v * 0.25503227f);
      } else if (n < 256){
        int h = n >> 5, d = n & 31;
        Kb[((size_t)(b*HEADS + h)*NKV + pos)*DDIM + d] = f2bf(v);
      } else {
        int c = n - 256, h = c >> 5, d = c & 31;
        VTb[((size_t)(b*HEADS + h)*DDIM + d)*NKV + pos] = f2bf(v);
      }
    }
  }
}

// Out projection: AO[M][256] bf16 @ woutT -> f32 + bias.
__global__ __launch_bounds__(256) void gemm_out(
    const unsigned short* __restrict__ X,
    const unsigned short* __restrict__ WT,
    float* __restrict__ FO,
    const float* __restrict__ bias)
{
  const int wid = threadIdx.x >> 6;
  const int lane = threadIdx.x & 63;
  const int l15 = lane & 15, g = lane >> 4;
  const int m0 = blockIdx.x * 64;
  const int n0 = blockIdx.y * 64 + wid * 16;
  f32x4 acc[4] = {{0,0,0,0},{0,0,0,0},{0,0,0,0},{0,0,0,0}};
  const unsigned short* xp = X + (size_t)(m0 + l15) * CDIM + g * 8;
  const unsigned short* wp = WT + (size_t)(n0 + l15) * CDIM + g * 8;
  #pragma unroll
  for (int k0 = 0; k0 < CDIM; k0 += 32){
    bf16x8 bfr = *(const bf16x8*)(wp + k0);
    #pragma unroll
    for (int i = 0; i < 4; ++i){
      bf16x8 afr = *(const bf16x8*)(xp + (size_t)i*16*CDIM + k0);
      acc[i] = __builtin_amdgcn_mfma_f32_16x16x32_bf16(afr, bfr, acc[i], 0, 0, 0);
    }
  }
  #pragma unroll
  for (int i = 0; i < 4; ++i){
    #pragma unroll
    for (int r = 0; r < 4; ++r){
      int m = m0 + i*16 + g*4 + r;
      int n = n0 + l15;
      FO[(size_t)m*CDIM + n] = acc[i][r] + bias[n];
    }
  }
}

// Flash attention v3: 32x32x16 MFMA, QBLK=32/wave, KVBLK=32, kv-split 4.
// Block = 1 q-tile x 4 kv-quarters -> grid 2048 = 8 blocks/CU = 8 waves/SIMD.
// Swapped QK^T, O^T accumulation, in-register P transpose, defer-max THR=8.
__global__ __launch_bounds__(256, 8) void attn3(
    const unsigned short* __restrict__ Qb,
    const unsigned short* __restrict__ Kb,
    const unsigned short* __restrict__ VT,
    unsigned short* __restrict__ AO)
{
  __shared__ float mrg[3][18][64];   // partials of waves 1..3: 16 acc regs + m + l
  const int wid = threadIdx.x >> 6;          // kv quarter
  const int lane = threadIdx.x & 63;
  const int l31 = lane & 31, g1 = lane >> 5;
  // bijective XCD swizzle over 2048 blocks: each XCD serves bh {x, x+8}
  const int lin = blockIdx.x;
  const int xcd = lin & 7;
  const int t = lin >> 3;                    // 0..255
  const int qtile = t & 127;
  const int bh = xcd + 8 * (t >> 7);
  const int q0 = qtile * 32;

  const unsigned short* Qp = Qb + ((size_t)bh * NQ + q0) * DDIM;
  const unsigned short* Kp = Kb + ((size_t)bh * NKV + wid * 1024) * DDIM;
  const unsigned short* Vp = VT + ((size_t)bh * DDIM + l31) * NKV + wid * 1024;

  // Q B-fragments (B[k=d][col=q=l31])
  const bf16x8 qf0 = *(const bf16x8*)(Qp + l31 * DDIM + 8 * g1);
  const bf16x8 qf1 = *(const bf16x8*)(Qp + l31 * DDIM + 16 + 8 * g1);

  f32x16 acc, csplat;
  #pragma unroll
  for (int j = 0; j < 16; ++j){ acc[j] = 0.0f; csplat[j] = 0.0f; }
  float mrun = 0.0f, lrun = 0.0f;

  for (int it = 0; it < 32; ++it){
    const unsigned short* kp = Kp + (size_t)(it * 32 + l31) * DDIM + 8 * g1;
    bf16x8 kf0 = *(const bf16x8*)(kp);        // A: K[kv=l31][d=8g1..]
    bf16x8 kf1 = *(const bf16x8*)(kp + 16);
    const unsigned short* vp = Vp + it * 32 + 8 * g1;
    bf16x8 vf0 = *(const bf16x8*)(vp);        // A: V^T[d=l31][kv=8g1..]
    bf16x8 vf1 = *(const bf16x8*)(vp + 16);

    // S^T = K·Q^T - m  (C = -m splat; col=q=l31, row-pattern=kv)
    __builtin_amdgcn_s_setprio(1);
    f32x16 s = __builtin_amdgcn_mfma_f32_32x32x16_bf16(kf0, qf0, csplat, 0, 0, 0);
    s = __builtin_amdgcn_mfma_f32_32x32x16_bf16(kf1, qf1, s, 0, 0, 0);
    __builtin_amdgcn_s_setprio(0);

    // per-lane max of 16 via max3-fusable triples: 5 triples + 15 -> 6 -> 2 -> 1
    float t0 = fmaxf(fmaxf(s[0],  s[1]),  s[2]);
    float t1 = fmaxf(fmaxf(s[3],  s[4]),  s[5]);
    float t2 = fmaxf(fmaxf(s[6],  s[7]),  s[8]);
    float t3 = fmaxf(fmaxf(s[9],  s[10]), s[11]);
    float t4 = fmaxf(fmaxf(s[12], s[13]), s[14]);
    float pmax = fmaxf(fmaxf(fmaxf(t0, t1), t2), fmaxf(fmaxf(t3, t4), s[15]));
    if (!__all(pmax <= 8.0f)){
      // rare rescale: per-q-row max across the two 32-lane halves
      float aw = pmax, bw = pmax;
      asm("v_permlane32_swap_b32 %0, %1" : "+v"(aw), "+v"(bw));
      float rm = fmaxf(fmaxf(aw, bw), 0.0f);
      float alpha = __builtin_amdgcn_exp2f(-rm);
      #pragma unroll
      for (int j = 0; j < 16; ++j){ s[j] -= rm; acc[j] *= alpha; }
      lrun *= alpha;
      mrun += rm;
      #pragma unroll
      for (int j = 0; j < 16; ++j) csplat[j] = -mrun;
    }
    #pragma unroll
    for (int j = 0; j < 16; ++j) s[j] = __builtin_amdgcn_exp2f(s[j]);
    float ps = ((s[0]+s[1]) + (s[2]+s[3])) + ((s[4]+s[5]) + (s[6]+s[7]))
             + (((s[8]+s[9]) + (s[10]+s[11])) + ((s[12]+s[13]) + (s[14]+s[15])));
    { float aw = ps, bw = ps;
      asm("v_permlane32_swap_b32 %0, %1" : "+v"(aw), "+v"(bw));
      ps = aw + bw; }
    lrun += ps;

    // P -> bf16 PV B-fragments, in-register (cvt_pk + permlane32_swap)
    unsigned int u0,u1,u2,u3,u4,u5,u6,u7;
    asm("v_cvt_pk_bf16_f32 %0, %1, %2" : "=v"(u0) : "v"(s[0]),  "v"(s[1]));
    asm("v_cvt_pk_bf16_f32 %0, %1, %2" : "=v"(u1) : "v"(s[2]),  "v"(s[3]));
    asm("v_cvt_pk_bf16_f32 %0, %1, %2" : "=v"(u2) : "v"(s[4]),  "v"(s[5]));
    asm("v_cvt_pk_bf16_f32 %0, %1, %2" : "=v"(u3) : "v"(s[6]),  "v"(s[7]));
    asm("v_cvt_pk_bf16_f32 %0, %1, %2" : "=v"(u4) : "v"(s[8]),  "v"(s[9]));
    asm("v_cvt_pk_bf16_f32 %0, %1, %2" : "=v"(u5) : "v"(s[10]), "v"(s[11]));
    asm("v_cvt_pk_bf16_f32 %0, %1, %2" : "=v"(u6) : "v"(s[12]), "v"(s[13]));
    asm("v_cvt_pk_bf16_f32 %0, %1, %2" : "=v"(u7) : "v"(s[14]), "v"(s[15]));
    asm("v_permlane32_swap_b32 %0, %1" : "+v"(u0), "+v"(u2));
    asm("v_permlane32_swap_b32 %0, %1" : "+v"(u1), "+v"(u3));
    asm("v_permlane32_swap_b32 %0, %1" : "+v"(u4), "+v"(u6));
    asm("v_permlane32_swap_b32 %0, %1" : "+v"(u5), "+v"(u7));
    union { unsigned int u[4]; bf16x8 v; } f0, f1;
    f0.u[0]=u0; f0.u[1]=u1; f0.u[2]=u2; f0.u[3]=u3;
    f1.u[0]=u4; f1.u[1]=u5; f1.u[2]=u6; f1.u[3]=u7;

    // O^T += V^T · P^T
    __builtin_amdgcn_s_setprio(1);
    acc = __builtin_amdgcn_mfma_f32_32x32x16_bf16(vf0, f0.v, acc, 0, 0, 0);
    acc = __builtin_amdgcn_mfma_f32_32x32x16_bf16(vf1, f1.v, acc, 0, 0, 0);
    __builtin_amdgcn_s_setprio(0);
  }

  // 4-way merge of kv-quarters, then wave 0 writes output
  if (wid != 0){
    #pragma unroll
    for (int j = 0; j < 16; ++j) mrg[wid-1][j][lane] = acc[j];
    mrg[wid-1][16][lane] = mrun;
    mrg[wid-1][17][lane] = lrun;
  }
  __syncthreads();
  if (wid == 0){
    float m1 = mrg[0][16][lane], m2 = mrg[1][16][lane], m3 = mrg[2][16][lane];
    float l1 = mrg[0][17][lane], l2 = mrg[1][17][lane], l3 = mrg[2][17][lane];
    float m = fmaxf(fmaxf(mrun, m1), fmaxf(m2, m3));
    float a0 = __builtin_amdgcn_exp2f(mrun - m);
    float a1 = __builtin_amdgcn_exp2f(m1 - m);
    float a2 = __builtin_amdgcn_exp2f(m2 - m);
    float a3 = __builtin_amdgcn_exp2f(m3 - m);
    float linv = 1.0f / (lrun*a0 + l1*a1 + l2*a2 + l3*a3);
    a0 *= linv; a1 *= linv; a2 *= linv; a3 *= linv;
    int b = bh >> 3, h = bh & 7;
    size_t rowbase = ((size_t)b * NQ + q0 + l31) * CDIM + h * DDIM;
    #pragma unroll
    for (int u = 0; u < 4; ++u){
      float o[4];
      #pragma unroll
      for (int r = 0; r < 4; ++r){
        int j = 4*u + r;
        o[r] = acc[j]*a0 + mrg[0][j][lane]*a1 + mrg[1][j][lane]*a2 + mrg[2][j][lane]*a3;
      }
      unsigned int w0, w1;
      asm("v_cvt_pk_bf16_f32 %0, %1, %2" : "=v"(w0) : "v"(o[0]), "v"(o[1]));
      asm("v_cvt_pk_bf16_f32 %0, %1, %2" : "=v"(w1) : "v"(o[2]), "v"(o[3]));
      unsigned int* dst = (unsigned int*)(AO + rowbase + 8*u + 4*g1);
      dst[0] = w0; dst[1] = w1;
    }
  }
}

extern "C" void kernel_launch(void* const* d_in, const int* in_sizes, int n_in,
                              void* d_out, int out_size, void* d_ws, size_t ws_size,
                              hipStream_t stream)
{
  const float* query     = (const float*)d_in[0];
  const float* key_value = (const float*)d_in[1];
  const float* w_q       = (const float*)d_in[2];
  const float* w_kv      = (const float*)d_in[3];
  const float* w_out     = (const float*)d_in[4];
  const float* b_out     = (const float*)d_in[5];
  float* out = (float*)d_out;
  char* ws = (char*)d_ws;
  unsigned short* qx    = (unsigned short*)(ws + 0);         // 8192*256 bf16
  unsigned short* kvx   = (unsigned short*)(ws + 4194304);   // 8192*256 bf16
  unsigned short* wqT   = (unsigned short*)(ws + 8388608);   // 256*256
  unsigned short* wkvT  = (unsigned short*)(ws + 8519680);   // 512*256
  unsigned short* woutT = (unsigned short*)(ws + 8781824);   // 256*256
  unsigned short* Qb    = (unsigned short*)(ws + 8912896);   // [2][8][4096][32]
  unsigned short* Kb    = (unsigned short*)(ws + 13107200);  // [2][8][4096][32]
  unsigned short* VTb   = (unsigned short*)(ws + 17301504);  // [2][8][32][4096]
  unsigned short* AO    = qx;                                // [8192][256] bf16 (qx dead)

  prep<<<3072, 256, 0, stream>>>(query, key_value, w_q, w_kv, w_out,
                                 qx, kvx, wqT, wkvT, woutT);
  gemm_qkv<<<dim3(128, 12), 256, 0, stream>>>(qx, kvx, wqT, wkvT, Qb, Kb, VTb);
  attn3<<<2048, 256, 0, stream>>>(Qb, Kb, VTb, AO);
  gemm_out<<<dim3(128, 4), 256, 0, stream>>>(AO, woutT, out, b_out);
}

// Round 4
// 154.645 us; speedup vs baseline: 3.7612x; 3.7612x over previous
//
#include <hip/hip_runtime.h>

typedef __attribute__((ext_vector_type(8))) short bf16x8;
typedef __attribute__((ext_vector_type(4))) float f32x4;
typedef __attribute__((ext_vector_type(16))) float f32x16;

#define NQ   4096
#define NKV  4096
#define CDIM 256
#define HEADS 8
#define DDIM 32

// f32 -> bf16 RNE
__device__ __forceinline__ unsigned short f2bf(float x){
  unsigned int u = __builtin_bit_cast(unsigned int, x);
  u = (u + 0x7FFFu + ((u >> 16) & 1u)) >> 16;
  return (unsigned short)u;
}

__device__ __forceinline__ void cvt8(const float* __restrict__ in,
                                     unsigned short* __restrict__ out, int i){
  const float4* p = (const float4*)in;
  float4 a = p[2*i], b = p[2*i+1];
  union { unsigned short u[8]; bf16x8 v; } o;
  o.u[0]=f2bf(a.x); o.u[1]=f2bf(a.y); o.u[2]=f2bf(a.z); o.u[3]=f2bf(a.w);
  o.u[4]=f2bf(b.x); o.u[5]=f2bf(b.y); o.u[6]=f2bf(b.z); o.u[7]=f2bf(b.w);
  ((bf16x8*)out)[i] = o.v;
}

// Convert activations to bf16 (same layout) and weights to bf16 transposed [N][K].
__global__ __launch_bounds__(256) void prep(
    const float* __restrict__ q, const float* __restrict__ kv,
    const float* __restrict__ wq, const float* __restrict__ wkv,
    const float* __restrict__ wout,
    unsigned short* __restrict__ qx, unsigned short* __restrict__ kvx,
    unsigned short* __restrict__ wqT, unsigned short* __restrict__ wkvT,
    unsigned short* __restrict__ woutT)
{
  int t = blockIdx.x * 256 + threadIdx.x;
  if (t < 262144){ cvt8(q, qx, t); }
  else if (t < 524288){ cvt8(kv, kvx, t - 262144); }
  else {
    int i = t - 524288;                       // 0 .. 262143
    if (i < 65536){ int n = i >> 8, k = i & 255; wqT[i] = f2bf(wq[k*256 + n]); }
    else if (i < 196608){ int j = i - 65536; int n = j >> 8, k = j & 255;
                          wkvT[j] = f2bf(wkv[k*512 + n]); }
    else { int j = i - 196608; int n = j >> 8, k = j & 255;
           woutT[j] = f2bf(wout[k*256 + n]); }
  }
}

// Fused Q + KV projection. blockIdx.y < 4 -> Q-mode (N=256); else KV-mode (N=512).
__global__ __launch_bounds__(256) void gemm_qkv(
    const unsigned short* __restrict__ qx,
    const unsigned short* __restrict__ kvx,
    const unsigned short* __restrict__ wqT,
    const unsigned short* __restrict__ wkvT,
    unsigned short* __restrict__ Qb,
    unsigned short* __restrict__ Kb,
    unsigned short* __restrict__ VTb)
{
  const int wid = threadIdx.x >> 6;
  const int lane = threadIdx.x & 63;
  const int l15 = lane & 15, g = lane >> 4;
  const int m0 = blockIdx.x * 64;
  const int mode = blockIdx.y >= 4;
  const int ny = mode ? (blockIdx.y - 4) : blockIdx.y;
  const int n0 = ny * 64 + wid * 16;
  const unsigned short* X  = mode ? kvx  : qx;
  const unsigned short* WT = mode ? wkvT : wqT;
  f32x4 acc[4] = {{0,0,0,0},{0,0,0,0},{0,0,0,0},{0,0,0,0}};
  const unsigned short* xp = X + (size_t)(m0 + l15) * CDIM + g * 8;
  const unsigned short* wp = WT + (size_t)(n0 + l15) * CDIM + g * 8;
  #pragma unroll
  for (int k0 = 0; k0 < CDIM; k0 += 32){
    bf16x8 bfr = *(const bf16x8*)(wp + k0);
    #pragma unroll
    for (int i = 0; i < 4; ++i){
      bf16x8 afr = *(const bf16x8*)(xp + (size_t)i*16*CDIM + k0);
      acc[i] = __builtin_amdgcn_mfma_f32_16x16x32_bf16(afr, bfr, acc[i], 0, 0, 0);
    }
  }
  #pragma unroll
  for (int i = 0; i < 4; ++i){
    #pragma unroll
    for (int r = 0; r < 4; ++r){
      int m = m0 + i*16 + g*4 + r;
      int n = n0 + l15;
      float v = acc[i][r];
      int b = m >> 12, pos = m & 4095;
      if (!mode){
        int h = n >> 5, d = n & 31;
        // scale = D^-0.5 * log2(e) folded into Q
        Qb[((size_t)(b*HEADS + h)*NQ + pos)*DDIM + d] = f2bf(v * 0.25503227f);
      } else if (n < 256){
        int h = n >> 5, d = n & 31;
        Kb[((size_t)(b*HEADS + h)*NKV + pos)*DDIM + d] = f2bf(v);
      } else {
        int c = n - 256, h = c >> 5, d = c & 31;
        VTb[((size_t)(b*HEADS + h)*DDIM + d)*NKV + pos] = f2bf(v);
      }
    }
  }
}

// Out projection: AO[M][256] bf16 @ woutT -> f32 + bias.
__global__ __launch_bounds__(256) void gemm_out(
    const unsigned short* __restrict__ X,
    const unsigned short* __restrict__ WT,
    float* __restrict__ FO,
    const float* __restrict__ bias)
{
  const int wid = threadIdx.x >> 6;
  const int lane = threadIdx.x & 63;
  const int l15 = lane & 15, g = lane >> 4;
  const int m0 = blockIdx.x * 64;
  const int n0 = blockIdx.y * 64 + wid * 16;
  f32x4 acc[4] = {{0,0,0,0},{0,0,0,0},{0,0,0,0},{0,0,0,0}};
  const unsigned short* xp = X + (size_t)(m0 + l15) * CDIM + g * 8;
  const unsigned short* wp = WT + (size_t)(n0 + l15) * CDIM + g * 8;
  #pragma unroll
  for (int k0 = 0; k0 < CDIM; k0 += 32){
    bf16x8 bfr = *(const bf16x8*)(wp + k0);
    #pragma unroll
    for (int i = 0; i < 4; ++i){
      bf16x8 afr = *(const bf16x8*)(xp + (size_t)i*16*CDIM + k0);
      acc[i] = __builtin_amdgcn_mfma_f32_16x16x32_bf16(afr, bfr, acc[i], 0, 0, 0);
    }
  }
  #pragma unroll
  for (int i = 0; i < 4; ++i){
    #pragma unroll
    for (int r = 0; r < 4; ++r){
      int m = m0 + i*16 + g*4 + r;
      int n = n0 + l15;
      FO[(size_t)m*CDIM + n] = acc[i][r] + bias[n];
    }
  }
}

// Flash attention v4: 32x32x16 MFMA, QBLK=32/wave, KVBLK=32, kv-split 4.
// Grid 2048 = 8 blocks/CU potential; launch_bounds(256,4) (NOT 8 — that spills).
// Persistent csplat replaced by per-iter C refill with -mrun (aliases s dest).
__global__ __launch_bounds__(256, 4) void attn4(
    const unsigned short* __restrict__ Qb,
    const unsigned short* __restrict__ Kb,
    const unsigned short* __restrict__ VT,
    unsigned short* __restrict__ AO)
{
  __shared__ float mrg[3][18][64];   // partials of waves 1..3: 16 acc regs + m + l
  const int wid = threadIdx.x >> 6;          // kv quarter
  const int lane = threadIdx.x & 63;
  const int l31 = lane & 31, g1 = lane >> 5;
  // bijective XCD swizzle over 2048 blocks: each XCD serves bh {x, x+8}
  const int lin = blockIdx.x;
  const int xcd = lin & 7;
  const int t = lin >> 3;                    // 0..255
  const int qtile = t & 127;
  const int bh = xcd + 8 * (t >> 7);
  const int q0 = qtile * 32;

  const unsigned short* Qp = Qb + ((size_t)bh * NQ + q0) * DDIM;
  const unsigned short* Kp = Kb + ((size_t)bh * NKV + wid * 1024) * DDIM;
  const unsigned short* Vp = VT + ((size_t)bh * DDIM + l31) * NKV + wid * 1024;

  // Q B-fragments (B[k=d][col=q=l31])
  const bf16x8 qf0 = *(const bf16x8*)(Qp + l31 * DDIM + 8 * g1);
  const bf16x8 qf1 = *(const bf16x8*)(Qp + l31 * DDIM + 16 + 8 * g1);

  f32x16 acc;
  #pragma unroll
  for (int j = 0; j < 16; ++j) acc[j] = 0.0f;
  float mrun = 0.0f, lrun = 0.0f, negm = 0.0f;

  for (int it = 0; it < 32; ++it){
    const unsigned short* kp = Kp + (size_t)(it * 32 + l31) * DDIM + 8 * g1;
    bf16x8 kf0 = *(const bf16x8*)(kp);        // A: K[kv=l31][d=8g1..]
    bf16x8 kf1 = *(const bf16x8*)(kp + 16);
    const unsigned short* vp = Vp + it * 32 + 8 * g1;
    bf16x8 vf0 = *(const bf16x8*)(vp);        // A: V^T[d=l31][kv=8g1..]
    bf16x8 vf1 = *(const bf16x8*)(vp + 16);

    // C = -m splat (refilled each iter; dest-aliased with s, no persistent regs)
    f32x16 s;
    #pragma unroll
    for (int j = 0; j < 16; ++j) s[j] = negm;
    // S^T = K·Q^T - m  (col=q=l31, row-pattern=kv)
    __builtin_amdgcn_s_setprio(1);
    s = __builtin_amdgcn_mfma_f32_32x32x16_bf16(kf0, qf0, s, 0, 0, 0);
    s = __builtin_amdgcn_mfma_f32_32x32x16_bf16(kf1, qf1, s, 0, 0, 0);
    __builtin_amdgcn_s_setprio(0);

    // per-lane max of 16 via max3-fusable triples
    float t0 = fmaxf(fmaxf(s[0],  s[1]),  s[2]);
    float t1 = fmaxf(fmaxf(s[3],  s[4]),  s[5]);
    float t2 = fmaxf(fmaxf(s[6],  s[7]),  s[8]);
    float t3 = fmaxf(fmaxf(s[9],  s[10]), s[11]);
    float t4 = fmaxf(fmaxf(s[12], s[13]), s[14]);
    float pmax = fmaxf(fmaxf(fmaxf(t0, t1), t2), fmaxf(fmaxf(t3, t4), s[15]));
    if (!__all(pmax <= 8.0f)){
      // rare rescale: per-q-row max across the two 32-lane halves
      float aw = pmax, bw = pmax;
      asm("v_permlane32_swap_b32 %0, %1" : "+v"(aw), "+v"(bw));
      float rm = fmaxf(fmaxf(aw, bw), 0.0f);
      float alpha = __builtin_amdgcn_exp2f(-rm);
      #pragma unroll
      for (int j = 0; j < 16; ++j){ s[j] -= rm; acc[j] *= alpha; }
      lrun *= alpha;
      mrun += rm;
      negm = -mrun;
    }
    #pragma unroll
    for (int j = 0; j < 16; ++j) s[j] = __builtin_amdgcn_exp2f(s[j]);
    float ps = ((s[0]+s[1]) + (s[2]+s[3])) + ((s[4]+s[5]) + (s[6]+s[7]))
             + (((s[8]+s[9]) + (s[10]+s[11])) + ((s[12]+s[13]) + (s[14]+s[15])));
    { float aw = ps, bw = ps;
      asm("v_permlane32_swap_b32 %0, %1" : "+v"(aw), "+v"(bw));
      ps = aw + bw; }
    lrun += ps;

    // P -> bf16 PV B-fragments, in-register (cvt_pk + permlane32_swap)
    unsigned int u0,u1,u2,u3,u4,u5,u6,u7;
    asm("v_cvt_pk_bf16_f32 %0, %1, %2" : "=v"(u0) : "v"(s[0]),  "v"(s[1]));
    asm("v_cvt_pk_bf16_f32 %0, %1, %2" : "=v"(u1) : "v"(s[2]),  "v"(s[3]));
    asm("v_cvt_pk_bf16_f32 %0, %1, %2" : "=v"(u2) : "v"(s[4]),  "v"(s[5]));
    asm("v_cvt_pk_bf16_f32 %0, %1, %2" : "=v"(u3) : "v"(s[6]),  "v"(s[7]));
    asm("v_cvt_pk_bf16_f32 %0, %1, %2" : "=v"(u4) : "v"(s[8]),  "v"(s[9]));
    asm("v_cvt_pk_bf16_f32 %0, %1, %2" : "=v"(u5) : "v"(s[10]), "v"(s[11]));
    asm("v_cvt_pk_bf16_f32 %0, %1, %2" : "=v"(u6) : "v"(s[12]), "v"(s[13]));
    asm("v_cvt_pk_bf16_f32 %0, %1, %2" : "=v"(u7) : "v"(s[14]), "v"(s[15]));
    asm("v_permlane32_swap_b32 %0, %1" : "+v"(u0), "+v"(u2));
    asm("v_permlane32_swap_b32 %0, %1" : "+v"(u1), "+v"(u3));
    asm("v_permlane32_swap_b32 %0, %1" : "+v"(u4), "+v"(u6));
    asm("v_permlane32_swap_b32 %0, %1" : "+v"(u5), "+v"(u7));
    union { unsigned int u[4]; bf16x8 v; } f0, f1;
    f0.u[0]=u0; f0.u[1]=u1; f0.u[2]=u2; f0.u[3]=u3;
    f1.u[0]=u4; f1.u[1]=u5; f1.u[2]=u6; f1.u[3]=u7;

    // O^T += V^T · P^T
    __builtin_amdgcn_s_setprio(1);
    acc = __builtin_amdgcn_mfma_f32_32x32x16_bf16(vf0, f0.v, acc, 0, 0, 0);
    acc = __builtin_amdgcn_mfma_f32_32x32x16_bf16(vf1, f1.v, acc, 0, 0, 0);
    __builtin_amdgcn_s_setprio(0);
  }

  // 4-way merge of kv-quarters, then wave 0 writes output
  if (wid != 0){
    #pragma unroll
    for (int j = 0; j < 16; ++j) mrg[wid-1][j][lane] = acc[j];
    mrg[wid-1][16][lane] = mrun;
    mrg[wid-1][17][lane] = lrun;
  }
  __syncthreads();
  if (wid == 0){
    float m1 = mrg[0][16][lane], m2 = mrg[1][16][lane], m3 = mrg[2][16][lane];
    float l1 = mrg[0][17][lane], l2 = mrg[1][17][lane], l3 = mrg[2][17][lane];
    float m = fmaxf(fmaxf(mrun, m1), fmaxf(m2, m3));
    float a0 = __builtin_amdgcn_exp2f(mrun - m);
    float a1 = __builtin_amdgcn_exp2f(m1 - m);
    float a2 = __builtin_amdgcn_exp2f(m2 - m);
    float a3 = __builtin_amdgcn_exp2f(m3 - m);
    float linv = 1.0f / (lrun*a0 + l1*a1 + l2*a2 + l3*a3);
    a0 *= linv; a1 *= linv; a2 *= linv; a3 *= linv;
    int b = bh >> 3, h = bh & 7;
    size_t rowbase = ((size_t)b * NQ + q0 + l31) * CDIM + h * DDIM;
    #pragma unroll
    for (int u = 0; u < 4; ++u){
      float o[4];
      #pragma unroll
      for (int r = 0; r < 4; ++r){
        int j = 4*u + r;
        o[r] = acc[j]*a0 + mrg[0][j][lane]*a1 + mrg[1][j][lane]*a2 + mrg[2][j][lane]*a3;
      }
      unsigned int w0, w1;
      asm("v_cvt_pk_bf16_f32 %0, %1, %2" : "=v"(w0) : "v"(o[0]), "v"(o[1]));
      asm("v_cvt_pk_bf16_f32 %0, %1, %2" : "=v"(w1) : "v"(o[2]), "v"(o[3]));
      unsigned int* dst = (unsigned int*)(AO + rowbase + 8*u + 4*g1);
      dst[0] = w0; dst[1] = w1;
    }
  }
}

extern "C" void kernel_launch(void* const* d_in, const int* in_sizes, int n_in,
                              void* d_out, int out_size, void* d_ws, size_t ws_size,
                              hipStream_t stream)
{
  const float* query     = (const float*)d_in[0];
  const float* key_value = (const float*)d_in[1];
  const float* w_q       = (const float*)d_in[2];
  const float* w_kv      = (const float*)d_in[3];
  const float* w_out     = (const float*)d_in[4];
  const float* b_out     = (const float*)d_in[5];
  float* out = (float*)d_out;
  char* ws = (char*)d_ws;
  unsigned short* qx    = (unsigned short*)(ws + 0);         // 8192*256 bf16
  unsigned short* kvx   = (unsigned short*)(ws + 4194304);   // 8192*256 bf16
  unsigned short* wqT   = (unsigned short*)(ws + 8388608);   // 256*256
  unsigned short* wkvT  = (unsigned short*)(ws + 8519680);   // 512*256
  unsigned short* woutT = (unsigned short*)(ws + 8781824);   // 256*256
  unsigned short* Qb    = (unsigned short*)(ws + 8912896);   // [2][8][4096][32]
  unsigned short* Kb    = (unsigned short*)(ws + 13107200);  // [2][8][4096][32]
  unsigned short* VTb   = (unsigned short*)(ws + 17301504);  // [2][8][32][4096]
  unsigned short* AO    = qx;                                // [8192][256] bf16 (qx dead)

  prep<<<3072, 256, 0, stream>>>(query, key_value, w_q, w_kv, w_out,
                                 qx, kvx, wqT, wkvT, woutT);
  gemm_qkv<<<dim3(128, 12), 256, 0, stream>>>(qx, kvx, wqT, wkvT, Qb, Kb, VTb);
  attn4<<<2048, 256, 0, stream>>>(Qb, Kb, VTb, AO);
  gemm_out<<<dim3(128, 4), 256, 0, stream>>>(AO, woutT, out, b_out);
}

// Round 5
// 122.548 us; speedup vs baseline: 4.7463x; 1.2619x over previous
//
#include <hip/hip_runtime.h>

typedef __attribute__((ext_vector_type(8))) short bf16x8;
typedef __attribute__((ext_vector_type(4))) float f32x4;
typedef __attribute__((ext_vector_type(16))) float f32x16;

#define NQ   4096
#define NKV  4096
#define CDIM 256
#define HEADS 8
#define DDIM 32

// f32 -> bf16 RNE
__device__ __forceinline__ unsigned short f2bf(float x){
  unsigned int u = __builtin_bit_cast(unsigned int, x);
  u = (u + 0x7FFFu + ((u >> 16) & 1u)) >> 16;
  return (unsigned short)u;
}

__device__ __forceinline__ void cvt8(const float* __restrict__ in,
                                     unsigned short* __restrict__ out, int i){
  const float4* p = (const float4*)in;
  float4 a = p[2*i], b = p[2*i+1];
  union { unsigned short u[8]; bf16x8 v; } o;
  o.u[0]=f2bf(a.x); o.u[1]=f2bf(a.y); o.u[2]=f2bf(a.z); o.u[3]=f2bf(a.w);
  o.u[4]=f2bf(b.x); o.u[5]=f2bf(b.y); o.u[6]=f2bf(b.z); o.u[7]=f2bf(b.w);
  ((bf16x8*)out)[i] = o.v;
}

// Convert activations to bf16 (same layout) and weights to bf16 transposed [N][K].
__global__ __launch_bounds__(256) void prep(
    const float* __restrict__ q, const float* __restrict__ kv,
    const float* __restrict__ wq, const float* __restrict__ wkv,
    const float* __restrict__ wout,
    unsigned short* __restrict__ qx, unsigned short* __restrict__ kvx,
    unsigned short* __restrict__ wqT, unsigned short* __restrict__ wkvT,
    unsigned short* __restrict__ woutT)
{
  int t = blockIdx.x * 256 + threadIdx.x;
  if (t < 262144){ cvt8(q, qx, t); }
  else if (t < 524288){ cvt8(kv, kvx, t - 262144); }
  else {
    int i = t - 524288;                       // 0 .. 262143
    if (i < 65536){ int n = i >> 8, k = i & 255; wqT[i] = f2bf(wq[k*256 + n]); }
    else if (i < 196608){ int j = i - 65536; int n = j >> 8, k = j & 255;
                          wkvT[j] = f2bf(wkv[k*512 + n]); }
    else { int j = i - 196608; int n = j >> 8, k = j & 255;
           woutT[j] = f2bf(wout[k*256 + n]); }
  }
}

// Fused Q + KV projection. blockIdx.y < 4 -> Q-mode (N=256); else KV-mode (N=512).
__global__ __launch_bounds__(256) void gemm_qkv(
    const unsigned short* __restrict__ qx,
    const unsigned short* __restrict__ kvx,
    const unsigned short* __restrict__ wqT,
    const unsigned short* __restrict__ wkvT,
    unsigned short* __restrict__ Qb,
    unsigned short* __restrict__ Kb,
    unsigned short* __restrict__ VTb)
{
  const int wid = threadIdx.x >> 6;
  const int lane = threadIdx.x & 63;
  const int l15 = lane & 15, g = lane >> 4;
  const int m0 = blockIdx.x * 64;
  const int mode = blockIdx.y >= 4;
  const int ny = mode ? (blockIdx.y - 4) : blockIdx.y;
  const int n0 = ny * 64 + wid * 16;
  const unsigned short* X  = mode ? kvx  : qx;
  const unsigned short* WT = mode ? wkvT : wqT;
  f32x4 acc[4] = {{0,0,0,0},{0,0,0,0},{0,0,0,0},{0,0,0,0}};
  const unsigned short* xp = X + (size_t)(m0 + l15) * CDIM + g * 8;
  const unsigned short* wp = WT + (size_t)(n0 + l15) * CDIM + g * 8;
  #pragma unroll
  for (int k0 = 0; k0 < CDIM; k0 += 32){
    bf16x8 bfr = *(const bf16x8*)(wp + k0);
    #pragma unroll
    for (int i = 0; i < 4; ++i){
      bf16x8 afr = *(const bf16x8*)(xp + (size_t)i*16*CDIM + k0);
      acc[i] = __builtin_amdgcn_mfma_f32_16x16x32_bf16(afr, bfr, acc[i], 0, 0, 0);
    }
  }
  #pragma unroll
  for (int i = 0; i < 4; ++i){
    #pragma unroll
    for (int r = 0; r < 4; ++r){
      int m = m0 + i*16 + g*4 + r;
      int n = n0 + l15;
      float v = acc[i][r];
      int b = m >> 12, pos = m & 4095;
      if (!mode){
        int h = n >> 5, d = n & 31;
        // scale = D^-0.5 * log2(e) folded into Q
        Qb[((size_t)(b*HEADS + h)*NQ + pos)*DDIM + d] = f2bf(v * 0.25503227f);
      } else if (n < 256){
        int h = n >> 5, d = n & 31;
        Kb[((size_t)(b*HEADS + h)*NKV + pos)*DDIM + d] = f2bf(v);
      } else {
        int c = n - 256, h = c >> 5, d = c & 31;
        VTb[((size_t)(b*HEADS + h)*DDIM + d)*NKV + pos] = f2bf(v);
      }
    }
  }
}

// Out projection: AO[M][256] bf16 @ woutT -> f32 + bias.
__global__ __launch_bounds__(256) void gemm_out(
    const unsigned short* __restrict__ X,
    const unsigned short* __restrict__ WT,
    float* __restrict__ FO,
    const float* __restrict__ bias)
{
  const int wid = threadIdx.x >> 6;
  const int lane = threadIdx.x & 63;
  const int l15 = lane & 15, g = lane >> 4;
  const int m0 = blockIdx.x * 64;
  const int n0 = blockIdx.y * 64 + wid * 16;
  f32x4 acc[4] = {{0,0,0,0},{0,0,0,0},{0,0,0,0},{0,0,0,0}};
  const unsigned short* xp = X + (size_t)(m0 + l15) * CDIM + g * 8;
  const unsigned short* wp = WT + (size_t)(n0 + l15) * CDIM + g * 8;
  #pragma unroll
  for (int k0 = 0; k0 < CDIM; k0 += 32){
    bf16x8 bfr = *(const bf16x8*)(wp + k0);
    #pragma unroll
    for (int i = 0; i < 4; ++i){
      bf16x8 afr = *(const bf16x8*)(xp + (size_t)i*16*CDIM + k0);
      acc[i] = __builtin_amdgcn_mfma_f32_16x16x32_bf16(afr, bfr, acc[i], 0, 0, 0);
    }
  }
  #pragma unroll
  for (int i = 0; i < 4; ++i){
    #pragma unroll
    for (int r = 0; r < 4; ++r){
      int m = m0 + i*16 + g*4 + r;
      int n = n0 + l15;
      FO[(size_t)m*CDIM + n] = acc[i][r] + bias[n];
    }
  }
}

// Flash attention v5: 4 waves x 32 q-rows (QBLK=128), full KV per block (no merge).
// K/V tiles staged to LDS in FRAGMENT ORDER via global_load_lds (per-lane global
// src, linear LDS dst) -> conflict-free ds_read_b128 AND 4x less TA line traffic
// (one staged tile shared by all 4 waves). Double-buffered, 1 barrier/tile.
__global__ __launch_bounds__(256, 4) void attn5(
    const unsigned short* __restrict__ Qb,
    const unsigned short* __restrict__ Kb,
    const unsigned short* __restrict__ VT,
    unsigned short* __restrict__ AO)
{
  __shared__ unsigned short lk[2][1024];   // [buf][2 chunks x 64 lanes x 8 elems] = 2KB/buf
  __shared__ unsigned short lv[2][1024];
  const int wid = threadIdx.x >> 6;
  const int lane = threadIdx.x & 63;
  const int l31 = lane & 31, g1 = lane >> 5;
  // XCD swizzle over 512 blocks: xcd x serves bh {x, x+8} (1MB K+V set in 4MB L2)
  const int lin = blockIdx.x;
  const int xcd = lin & 7;
  const int j = lin >> 3;                   // 0..63
  const int qg = j & 31;
  const int bh = xcd + 8 * (j >> 5);
  const int q0w = qg * 128 + wid * 32;      // this wave's 32 q-rows

  const unsigned short* Qp = Qb + ((size_t)bh * NQ + q0w) * DDIM;
  const unsigned short* Kp = Kb + (size_t)bh * NKV * DDIM;
  const unsigned short* Vp = VT + (size_t)bh * DDIM * NKV;

  // Q B-fragments (B[k=d][col=q=l31])
  const bf16x8 qf0 = *(const bf16x8*)(Qp + l31 * DDIM + 8 * g1);
  const bf16x8 qf1 = *(const bf16x8*)(Qp + l31 * DDIM + 16 + 8 * g1);

  // per-wave staging role: wave wid stages chunk wid each tile (1KB = 64 lanes x 16B)
  // chunk 0: kf0 = K[kv0+l31][8g1..]   chunk 1: kf1 = K[kv0+l31][16+8g1..]
  // chunk 2: vf0 = VT[l31][kv0+8g1..]  chunk 3: vf1 = VT[l31][kv0+16+8g1..]
  const unsigned short* gsrc;
  int gstep;
  unsigned short* lbase;                    // dst chunk base (uniform per wave)
  if (wid == 0){ gsrc = Kp + l31*DDIM + 8*g1;            gstep = 1024; lbase = &lk[0][0]; }
  else if (wid == 1){ gsrc = Kp + l31*DDIM + 16 + 8*g1;  gstep = 1024; lbase = &lk[0][512]; }
  else if (wid == 2){ gsrc = Vp + (size_t)l31*NKV + 8*g1;      gstep = 32; lbase = &lv[0][0]; }
  else { gsrc = Vp + (size_t)l31*NKV + 16 + 8*g1;              gstep = 32; lbase = &lv[0][512]; }

  f32x16 acc, csplat;
  #pragma unroll
  for (int jj = 0; jj < 16; ++jj){ acc[jj] = 0.0f; csplat[jj] = 0.0f; }
  float mrun = 0.0f, lrun = 0.0f;

  // prologue: stage tile 0 into buf 0
  __builtin_amdgcn_global_load_lds((const unsigned int*)gsrc, (unsigned int*)lbase, 16, 0, 0);
  gsrc += gstep;
  __syncthreads();

  for (int t = 0; t < 128; ++t){
    const int cur = t & 1;
    // stage tile t+1 into the other buffer (issue early, drain at the barrier)
    if (t < 127){
      __builtin_amdgcn_global_load_lds((const unsigned int*)gsrc,
          (unsigned int*)(lbase + (cur ^ 1) * 1024), 16, 0, 0);
      gsrc += gstep;
    }
    // fragments from LDS (linear lane*16B -> conflict-free ds_read_b128)
    bf16x8 kf0 = *(const bf16x8*)(&lk[cur][lane*8]);
    bf16x8 kf1 = *(const bf16x8*)(&lk[cur][512 + lane*8]);
    bf16x8 vf0 = *(const bf16x8*)(&lv[cur][lane*8]);
    bf16x8 vf1 = *(const bf16x8*)(&lv[cur][512 + lane*8]);

    // S^T = K·Q^T - m  (col=q=l31, row-pattern=kv)
    __builtin_amdgcn_s_setprio(1);
    f32x16 s = __builtin_amdgcn_mfma_f32_32x32x16_bf16(kf0, qf0, csplat, 0, 0, 0);
    s = __builtin_amdgcn_mfma_f32_32x32x16_bf16(kf1, qf1, s, 0, 0, 0);
    __builtin_amdgcn_s_setprio(0);

    // per-lane max of 16 via max3-fusable triples
    float t0 = fmaxf(fmaxf(s[0],  s[1]),  s[2]);
    float t1 = fmaxf(fmaxf(s[3],  s[4]),  s[5]);
    float t2 = fmaxf(fmaxf(s[6],  s[7]),  s[8]);
    float t3 = fmaxf(fmaxf(s[9],  s[10]), s[11]);
    float t4 = fmaxf(fmaxf(s[12], s[13]), s[14]);
    float pmax = fmaxf(fmaxf(fmaxf(t0, t1), t2), fmaxf(fmaxf(t3, t4), s[15]));
    if (!__all(pmax <= 8.0f)){
      // rare rescale: per-q-row max across the two 32-lane halves
      float aw = pmax, bw = pmax;
      asm("v_permlane32_swap_b32 %0, %1" : "+v"(aw), "+v"(bw));
      float rm = fmaxf(fmaxf(aw, bw), 0.0f);
      float alpha = __builtin_amdgcn_exp2f(-rm);
      #pragma unroll
      for (int jj = 0; jj < 16; ++jj){ s[jj] -= rm; acc[jj] *= alpha; }
      lrun *= alpha;
      mrun += rm;
      #pragma unroll
      for (int jj = 0; jj < 16; ++jj) csplat[jj] = -mrun;
    }
    #pragma unroll
    for (int jj = 0; jj < 16; ++jj) s[jj] = __builtin_amdgcn_exp2f(s[jj]);
    float ps = ((s[0]+s[1]) + (s[2]+s[3])) + ((s[4]+s[5]) + (s[6]+s[7]))
             + (((s[8]+s[9]) + (s[10]+s[11])) + ((s[12]+s[13]) + (s[14]+s[15])));
    { float aw = ps, bw = ps;
      asm("v_permlane32_swap_b32 %0, %1" : "+v"(aw), "+v"(bw));
      ps = aw + bw; }
    lrun += ps;

    // P -> bf16 PV B-fragments, in-register (cvt_pk + permlane32_swap)
    unsigned int u0,u1,u2,u3,u4,u5,u6,u7;
    asm("v_cvt_pk_bf16_f32 %0, %1, %2" : "=v"(u0) : "v"(s[0]),  "v"(s[1]));
    asm("v_cvt_pk_bf16_f32 %0, %1, %2" : "=v"(u1) : "v"(s[2]),  "v"(s[3]));
    asm("v_cvt_pk_bf16_f32 %0, %1, %2" : "=v"(u2) : "v"(s[4]),  "v"(s[5]));
    asm("v_cvt_pk_bf16_f32 %0, %1, %2" : "=v"(u3) : "v"(s[6]),  "v"(s[7]));
    asm("v_cvt_pk_bf16_f32 %0, %1, %2" : "=v"(u4) : "v"(s[8]),  "v"(s[9]));
    asm("v_cvt_pk_bf16_f32 %0, %1, %2" : "=v"(u5) : "v"(s[10]), "v"(s[11]));
    asm("v_cvt_pk_bf16_f32 %0, %1, %2" : "=v"(u6) : "v"(s[12]), "v"(s[13]));
    asm("v_cvt_pk_bf16_f32 %0, %1, %2" : "=v"(u7) : "v"(s[14]), "v"(s[15]));
    asm("v_permlane32_swap_b32 %0, %1" : "+v"(u0), "+v"(u2));
    asm("v_permlane32_swap_b32 %0, %1" : "+v"(u1), "+v"(u3));
    asm("v_permlane32_swap_b32 %0, %1" : "+v"(u4), "+v"(u6));
    asm("v_permlane32_swap_b32 %0, %1" : "+v"(u5), "+v"(u7));
    union { unsigned int u[4]; bf16x8 v; } f0, f1;
    f0.u[0]=u0; f0.u[1]=u1; f0.u[2]=u2; f0.u[3]=u3;
    f1.u[0]=u4; f1.u[1]=u5; f1.u[2]=u6; f1.u[3]=u7;

    // O^T += V^T · P^T
    __builtin_amdgcn_s_setprio(1);
    acc = __builtin_amdgcn_mfma_f32_32x32x16_bf16(vf0, f0.v, acc, 0, 0, 0);
    acc = __builtin_amdgcn_mfma_f32_32x32x16_bf16(vf1, f1.v, acc, 0, 0, 0);
    __builtin_amdgcn_s_setprio(0);

    // barrier: (compiler drains vmcnt here) -> tile t+1 staged, buf cur free
    __syncthreads();
  }

  // epilogue: each wave owns its q-tile fully (no merge)
  float linv = 1.0f / lrun;
  int b = bh >> 3, h = bh & 7;
  size_t rowbase = ((size_t)b * NQ + q0w + l31) * CDIM + h * DDIM;
  #pragma unroll
  for (int u = 0; u < 4; ++u){
    float o0 = acc[4*u+0] * linv;
    float o1 = acc[4*u+1] * linv;
    float o2 = acc[4*u+2] * linv;
    float o3 = acc[4*u+3] * linv;
    unsigned int w0, w1;
    asm("v_cvt_pk_bf16_f32 %0, %1, %2" : "=v"(w0) : "v"(o0), "v"(o1));
    asm("v_cvt_pk_bf16_f32 %0, %1, %2" : "=v"(w1) : "v"(o2), "v"(o3));
    unsigned int* dst = (unsigned int*)(AO + rowbase + 8*u + 4*g1);
    dst[0] = w0; dst[1] = w1;
  }
}

extern "C" void kernel_launch(void* const* d_in, const int* in_sizes, int n_in,
                              void* d_out, int out_size, void* d_ws, size_t ws_size,
                              hipStream_t stream)
{
  const float* query     = (const float*)d_in[0];
  const float* key_value = (const float*)d_in[1];
  const float* w_q       = (const float*)d_in[2];
  const float* w_kv      = (const float*)d_in[3];
  const float* w_out     = (const float*)d_in[4];
  const float* b_out     = (const float*)d_in[5];
  float* out = (float*)d_out;
  char* ws = (char*)d_ws;
  unsigned short* qx    = (unsigned short*)(ws + 0);         // 8192*256 bf16
  unsigned short* kvx   = (unsigned short*)(ws + 4194304);   // 8192*256 bf16
  unsigned short* wqT   = (unsigned short*)(ws + 8388608);   // 256*256
  unsigned short* wkvT  = (unsigned short*)(ws + 8519680);   // 512*256
  unsigned short* woutT = (unsigned short*)(ws + 8781824);   // 256*256
  unsigned short* Qb    = (unsigned short*)(ws + 8912896);   // [2][8][4096][32]
  unsigned short* Kb    = (unsigned short*)(ws + 13107200);  // [2][8][4096][32]
  unsigned short* VTb   = (unsigned short*)(ws + 17301504);  // [2][8][32][4096]
  unsigned short* AO    = qx;                                // [8192][256] bf16 (qx dead)

  prep<<<3072, 256, 0, stream>>>(query, key_value, w_q, w_kv, w_out,
                                 qx, kvx, wqT, wkvT, woutT);
  gemm_qkv<<<dim3(128, 12), 256, 0, stream>>>(qx, kvx, wqT, wkvT, Qb, Kb, VTb);
  attn5<<<512, 256, 0, stream>>>(Qb, Kb, VTb, AO);
  gemm_out<<<dim3(128, 4), 256, 0, stream>>>(AO, woutT, out, b_out);
}

// Round 8
// 119.787 us; speedup vs baseline: 4.8557x; 1.0230x over previous
//
#include <hip/hip_runtime.h>

typedef __attribute__((ext_vector_type(8))) short bf16x8;
typedef __attribute__((ext_vector_type(4))) float f32x4;
typedef __attribute__((ext_vector_type(16))) float f32x16;

#define NQ   4096
#define NKV  4096
#define CDIM 256
#define HEADS 8
#define DDIM 32

// f32 -> bf16 RNE
__device__ __forceinline__ unsigned short f2bf(float x){
  unsigned int u = __builtin_bit_cast(unsigned int, x);
  u = (u + 0x7FFFu + ((u >> 16) & 1u)) >> 16;
  return (unsigned short)u;
}

__device__ __forceinline__ void cvt8(const float* __restrict__ in,
                                     unsigned short* __restrict__ out, int i){
  const float4* p = (const float4*)in;
  float4 a = p[2*i], b = p[2*i+1];
  union { unsigned short u[8]; bf16x8 v; } o;
  o.u[0]=f2bf(a.x); o.u[1]=f2bf(a.y); o.u[2]=f2bf(a.z); o.u[3]=f2bf(a.w);
  o.u[4]=f2bf(b.x); o.u[5]=f2bf(b.y); o.u[6]=f2bf(b.z); o.u[7]=f2bf(b.w);
  ((bf16x8*)out)[i] = o.v;
}

// Convert activations to bf16 (same layout) and weights to bf16 transposed [N][K].
__global__ __launch_bounds__(256) void prep(
    const float* __restrict__ q, const float* __restrict__ kv,
    const float* __restrict__ wq, const float* __restrict__ wkv,
    const float* __restrict__ wout,
    unsigned short* __restrict__ qx, unsigned short* __restrict__ kvx,
    unsigned short* __restrict__ wqT, unsigned short* __restrict__ wkvT,
    unsigned short* __restrict__ woutT)
{
  int t = blockIdx.x * 256 + threadIdx.x;
  if (t < 262144){ cvt8(q, qx, t); }
  else if (t < 524288){ cvt8(kv, kvx, t - 262144); }
  else {
    int i = t - 524288;                       // 0 .. 262143
    if (i < 65536){ int n = i >> 8, k = i & 255; wqT[i] = f2bf(wq[k*256 + n]); }
    else if (i < 196608){ int j = i - 65536; int n = j >> 8, k = j & 255;
                          wkvT[j] = f2bf(wkv[k*512 + n]); }
    else { int j = i - 196608; int n = j >> 8, k = j & 255;
           woutT[j] = f2bf(wout[k*256 + n]); }
  }
}

// Fused Q + KV projection. blockIdx.y < 4 -> Q-mode (N=256); else KV-mode (N=512).
__global__ __launch_bounds__(256) void gemm_qkv(
    const unsigned short* __restrict__ qx,
    const unsigned short* __restrict__ kvx,
    const unsigned short* __restrict__ wqT,
    const unsigned short* __restrict__ wkvT,
    unsigned short* __restrict__ Qb,
    unsigned short* __restrict__ Kb,
    unsigned short* __restrict__ VTb)
{
  const int wid = threadIdx.x >> 6;
  const int lane = threadIdx.x & 63;
  const int l15 = lane & 15, g = lane >> 4;
  const int m0 = blockIdx.x * 64;
  const int mode = blockIdx.y >= 4;
  const int ny = mode ? (blockIdx.y - 4) : blockIdx.y;
  const int n0 = ny * 64 + wid * 16;
  const unsigned short* X  = mode ? kvx  : qx;
  const unsigned short* WT = mode ? wkvT : wqT;
  f32x4 acc[4] = {{0,0,0,0},{0,0,0,0},{0,0,0,0},{0,0,0,0}};
  const unsigned short* xp = X + (size_t)(m0 + l15) * CDIM + g * 8;
  const unsigned short* wp = WT + (size_t)(n0 + l15) * CDIM + g * 8;
  #pragma unroll
  for (int k0 = 0; k0 < CDIM; k0 += 32){
    bf16x8 bfr = *(const bf16x8*)(wp + k0);
    #pragma unroll
    for (int i = 0; i < 4; ++i){
      bf16x8 afr = *(const bf16x8*)(xp + (size_t)i*16*CDIM + k0);
      acc[i] = __builtin_amdgcn_mfma_f32_16x16x32_bf16(afr, bfr, acc[i], 0, 0, 0);
    }
  }
  #pragma unroll
  for (int i = 0; i < 4; ++i){
    #pragma unroll
    for (int r = 0; r < 4; ++r){
      int m = m0 + i*16 + g*4 + r;
      int n = n0 + l15;
      float v = acc[i][r];
      int b = m >> 12, pos = m & 4095;
      if (!mode){
        int h = n >> 5, d = n & 31;
        // scale = D^-0.5 * log2(e) folded into Q
        Qb[((size_t)(b*HEADS + h)*NQ + pos)*DDIM + d] = f2bf(v * 0.25503227f);
      } else if (n < 256){
        int h = n >> 5, d = n & 31;
        Kb[((size_t)(b*HEADS + h)*NKV + pos)*DDIM + d] = f2bf(v);
      } else {
        int c = n - 256, h = c >> 5, d = c & 31;
        VTb[((size_t)(b*HEADS + h)*DDIM + d)*NKV + pos] = f2bf(v);
      }
    }
  }
}

// Out projection: AO2 [bh][q][32] bf16 @ woutT -> f32 out + bias.
// A-fragment k-index maps as k = 32*h + d: k-step kk reads head kk's d-slice.
__global__ __launch_bounds__(256) void gemm_out(
    const unsigned short* __restrict__ AO2,
    const unsigned short* __restrict__ WT,
    float* __restrict__ FO,
    const float* __restrict__ bias)
{
  const int wid = threadIdx.x >> 6;
  const int lane = threadIdx.x & 63;
  const int l15 = lane & 15, g = lane >> 4;
  const int m0 = blockIdx.x * 64;
  const int n0 = blockIdx.y * 64 + wid * 16;
  const int base_b = m0 >> 12, pos0 = m0 & 4095;
  f32x4 acc[4] = {{0,0,0,0},{0,0,0,0},{0,0,0,0},{0,0,0,0}};
  const unsigned short* wp = WT + (size_t)(n0 + l15) * CDIM + g * 8;
  #pragma unroll
  for (int k0 = 0; k0 < CDIM; k0 += 32){
    bf16x8 bfr = *(const bf16x8*)(wp + k0);
    const int h = k0 >> 5;
    const unsigned short* xp = AO2
        + ((size_t)(base_b*HEADS + h)*NQ + pos0 + l15)*DDIM + g*8;
    #pragma unroll
    for (int i = 0; i < 4; ++i){
      bf16x8 afr = *(const bf16x8*)(xp + (size_t)i*16*DDIM);
      acc[i] = __builtin_amdgcn_mfma_f32_16x16x32_bf16(afr, bfr, acc[i], 0, 0, 0);
    }
  }
  #pragma unroll
  for (int i = 0; i < 4; ++i){
    #pragma unroll
    for (int r = 0; r < 4; ++r){
      int m = m0 + i*16 + g*4 + r;
      int n = n0 + l15;
      FO[(size_t)m*CDIM + n] = acc[i][r] + bias[n];
    }
  }
}

// Flash attention v8: exact R5 (passing) body; kv split across BLOCKS.
// Grid 1024 = 16 bh x 32 qgroups x 2 kv-halves -> 4 blocks/CU = 4 waves/SIMD.
// Epilogue writes unnormalized O^T partials (f32) + (m,l); merged by attn_merge.
__global__ __launch_bounds__(256, 4) void attn8(
    const unsigned short* __restrict__ Qb,
    const unsigned short* __restrict__ Kb,
    const unsigned short* __restrict__ VT,
    float* __restrict__ P0, float* __restrict__ P1,
    float* __restrict__ ml)
{
  __shared__ unsigned short lk[2][1024];   // [buf][2 chunks x 64 lanes x 8 elems]
  __shared__ unsigned short lv[2][1024];
  const int wid = threadIdx.x >> 6;
  const int lane = threadIdx.x & 63;
  const int l31 = lane & 31, g1 = lane >> 5;
  // decomposition: xcd-swizzled; each XCD serves bh {x, x+8}, both kv-halves
  const int lin = blockIdx.x;
  const int xcd = lin & 7;
  const int j = lin >> 3;                   // 0..127
  const int qg = j & 31;
  const int kvhalf = (j >> 5) & 1;
  const int bh = xcd + 8 * (j >> 6);
  const int q0w = qg * 128 + wid * 32;      // this wave's 32 q-rows

  const unsigned short* Qp  = Qb + ((size_t)bh * NQ + q0w) * DDIM;
  const unsigned short* KpH = Kb + ((size_t)bh * NKV + kvhalf * 2048) * DDIM;
  const unsigned short* VpH = VT + (size_t)bh * DDIM * NKV + kvhalf * 2048;

  // Q B-fragments (B[k=d][col=q=l31])
  const bf16x8 qf0 = *(const bf16x8*)(Qp + l31 * DDIM + 8 * g1);
  const bf16x8 qf1 = *(const bf16x8*)(Qp + l31 * DDIM + 16 + 8 * g1);

  // per-wave staging role (identical to R5): wave wid stages chunk wid
  const unsigned short* gsrc;
  int gstep;
  unsigned short* lbase;
  if (wid == 0){ gsrc = KpH + l31*DDIM + 8*g1;            gstep = 1024; lbase = &lk[0][0]; }
  else if (wid == 1){ gsrc = KpH + l31*DDIM + 16 + 8*g1;  gstep = 1024; lbase = &lk[0][512]; }
  else if (wid == 2){ gsrc = VpH + (size_t)l31*NKV + 8*g1;      gstep = 32; lbase = &lv[0][0]; }
  else { gsrc = VpH + (size_t)l31*NKV + 16 + 8*g1;              gstep = 32; lbase = &lv[0][512]; }

  f32x16 acc, csplat;
  #pragma unroll
  for (int jj = 0; jj < 16; ++jj){ acc[jj] = 0.0f; csplat[jj] = 0.0f; }
  float mrun = 0.0f, lrun = 0.0f;

  // prologue: stage tile 0 into buf 0
  __builtin_amdgcn_global_load_lds((const unsigned int*)gsrc, (unsigned int*)lbase, 16, 0, 0);
  gsrc += gstep;
  __syncthreads();

  for (int t = 0; t < 64; ++t){
    const int cur = t & 1;
    if (t < 63){
      __builtin_amdgcn_global_load_lds((const unsigned int*)gsrc,
          (unsigned int*)(lbase + (cur ^ 1) * 1024), 16, 0, 0);
      gsrc += gstep;
    }
    // fragments from LDS (linear lane*16B -> conflict-free ds_read_b128)
    bf16x8 kf0 = *(const bf16x8*)(&lk[cur][lane*8]);
    bf16x8 kf1 = *(const bf16x8*)(&lk[cur][512 + lane*8]);
    bf16x8 vf0 = *(const bf16x8*)(&lv[cur][lane*8]);
    bf16x8 vf1 = *(const bf16x8*)(&lv[cur][512 + lane*8]);

    // S^T = K·Q^T - m  (col=q=l31, row-pattern=kv)
    __builtin_amdgcn_s_setprio(1);
    f32x16 s = __builtin_amdgcn_mfma_f32_32x32x16_bf16(kf0, qf0, csplat, 0, 0, 0);
    s = __builtin_amdgcn_mfma_f32_32x32x16_bf16(kf1, qf1, s, 0, 0, 0);
    __builtin_amdgcn_s_setprio(0);

    // per-lane max of 16 via max3-fusable triples
    float t0 = fmaxf(fmaxf(s[0],  s[1]),  s[2]);
    float t1 = fmaxf(fmaxf(s[3],  s[4]),  s[5]);
    float t2 = fmaxf(fmaxf(s[6],  s[7]),  s[8]);
    float t3 = fmaxf(fmaxf(s[9],  s[10]), s[11]);
    float t4 = fmaxf(fmaxf(s[12], s[13]), s[14]);
    float pmax = fmaxf(fmaxf(fmaxf(t0, t1), t2), fmaxf(fmaxf(t3, t4), s[15]));
    if (!__all(pmax <= 8.0f)){
      // rare rescale: per-q-row max across the two 32-lane halves
      float aw = pmax, bw = pmax;
      asm("v_permlane32_swap_b32 %0, %1" : "+v"(aw), "+v"(bw));
      float rm = fmaxf(fmaxf(aw, bw), 0.0f);
      float alpha = __builtin_amdgcn_exp2f(-rm);
      #pragma unroll
      for (int jj = 0; jj < 16; ++jj){ s[jj] -= rm; acc[jj] *= alpha; }
      lrun *= alpha;
      mrun += rm;
      #pragma unroll
      for (int jj = 0; jj < 16; ++jj) csplat[jj] = -mrun;
    }
    #pragma unroll
    for (int jj = 0; jj < 16; ++jj) s[jj] = __builtin_amdgcn_exp2f(s[jj]);
    float ps = ((s[0]+s[1]) + (s[2]+s[3])) + ((s[4]+s[5]) + (s[6]+s[7]))
             + (((s[8]+s[9]) + (s[10]+s[11])) + ((s[12]+s[13]) + (s[14]+s[15])));
    { float aw = ps, bw = ps;
      asm("v_permlane32_swap_b32 %0, %1" : "+v"(aw), "+v"(bw));
      ps = aw + bw; }
    lrun += ps;

    // P -> bf16 PV B-fragments, in-register (cvt_pk + permlane32_swap)
    unsigned int u0,u1,u2,u3,u4,u5,u6,u7;
    asm("v_cvt_pk_bf16_f32 %0, %1, %2" : "=v"(u0) : "v"(s[0]),  "v"(s[1]));
    asm("v_cvt_pk_bf16_f32 %0, %1, %2" : "=v"(u1) : "v"(s[2]),  "v"(s[3]));
    asm("v_cvt_pk_bf16_f32 %0, %1, %2" : "=v"(u2) : "v"(s[4]),  "v"(s[5]));
    asm("v_cvt_pk_bf16_f32 %0, %1, %2" : "=v"(u3) : "v"(s[6]),  "v"(s[7]));
    asm("v_cvt_pk_bf16_f32 %0, %1, %2" : "=v"(u4) : "v"(s[8]),  "v"(s[9]));
    asm("v_cvt_pk_bf16_f32 %0, %1, %2" : "=v"(u5) : "v"(s[10]), "v"(s[11]));
    asm("v_cvt_pk_bf16_f32 %0, %1, %2" : "=v"(u6) : "v"(s[12]), "v"(s[13]));
    asm("v_cvt_pk_bf16_f32 %0, %1, %2" : "=v"(u7) : "v"(s[14]), "v"(s[15]));
    asm("v_permlane32_swap_b32 %0, %1" : "+v"(u0), "+v"(u2));
    asm("v_permlane32_swap_b32 %0, %1" : "+v"(u1), "+v"(u3));
    asm("v_permlane32_swap_b32 %0, %1" : "+v"(u4), "+v"(u6));
    asm("v_permlane32_swap_b32 %0, %1" : "+v"(u5), "+v"(u7));
    union { unsigned int u[4]; bf16x8 v; } f0, f1;
    f0.u[0]=u0; f0.u[1]=u1; f0.u[2]=u2; f0.u[3]=u3;
    f1.u[0]=u4; f1.u[1]=u5; f1.u[2]=u6; f1.u[3]=u7;

    // O^T += V^T · P^T
    __builtin_amdgcn_s_setprio(1);
    acc = __builtin_amdgcn_mfma_f32_32x32x16_bf16(vf0, f0.v, acc, 0, 0, 0);
    acc = __builtin_amdgcn_mfma_f32_32x32x16_bf16(vf1, f1.v, acc, 0, 0, 0);
    __builtin_amdgcn_s_setprio(0);

    __syncthreads();
  }

  // epilogue: write unnormalized partials. lane(l31,g1) holds O[q=l31][d=(jj&3)+8*(jj>>2)+4*g1]
  float* Pp = (kvhalf ? P1 : P0) + ((size_t)bh * NQ + q0w + l31) * DDIM;
  #pragma unroll
  for (int u = 0; u < 4; ++u){
    float4 v4 = make_float4(acc[4*u+0], acc[4*u+1], acc[4*u+2], acc[4*u+3]);
    *(float4*)(Pp + 8*u + 4*g1) = v4;
  }
  if (g1 == 0){
    size_t ridx = (size_t)bh * NQ + q0w + l31;
    ml[(size_t)(kvhalf*2 + 0) * (16*NQ) + ridx] = mrun;
    ml[(size_t)(kvhalf*2 + 1) * (16*NQ) + ridx] = lrun;
  }
}

// Merge the two kv-half partials -> bf16 AO2 [bh][q][32].
__global__ __launch_bounds__(256) void attn_merge(
    const float* __restrict__ P0, const float* __restrict__ P1,
    const float* __restrict__ ml, unsigned short* __restrict__ AO2)
{
  const size_t idx = (size_t)blockIdx.x * 256 + threadIdx.x;   // bh*4096 + q
  const size_t R = (size_t)16 * NQ;
  float m0 = ml[idx], l0 = ml[R + idx];
  float m1 = ml[2*R + idx], l1 = ml[3*R + idx];
  float m = fmaxf(m0, m1);
  float a0 = __builtin_amdgcn_exp2f(m0 - m);
  float a1 = __builtin_amdgcn_exp2f(m1 - m);
  float linv = 1.0f / (l0*a0 + l1*a1);
  a0 *= linv; a1 *= linv;
  const float4* p0 = (const float4*)(P0 + idx*DDIM);
  const float4* p1 = (const float4*)(P1 + idx*DDIM);
  unsigned int ow[16];                                   // FIXED: was [8] (overflow)
  #pragma unroll
  for (int u = 0; u < 8; ++u){
    float4 x0 = p0[u], x1 = p1[u];
    float o0 = x0.x*a0 + x1.x*a1;
    float o1 = x0.y*a0 + x1.y*a1;
    float o2 = x0.z*a0 + x1.z*a1;
    float o3 = x0.w*a0 + x1.w*a1;
    unsigned int w0, w1;
    asm("v_cvt_pk_bf16_f32 %0, %1, %2" : "=v"(w0) : "v"(o0), "v"(o1));
    asm("v_cvt_pk_bf16_f32 %0, %1, %2" : "=v"(w1) : "v"(o2), "v"(o3));
    ow[2*u] = w0; ow[2*u+1] = w1;
  }
  uint4* dst = (uint4*)(AO2 + idx*DDIM);
  dst[0] = make_uint4(ow[0],  ow[1],  ow[2],  ow[3]);    // FIXED: write all 4
  dst[1] = make_uint4(ow[4],  ow[5],  ow[6],  ow[7]);
  dst[2] = make_uint4(ow[8],  ow[9],  ow[10], ow[11]);
  dst[3] = make_uint4(ow[12], ow[13], ow[14], ow[15]);
}

extern "C" void kernel_launch(void* const* d_in, const int* in_sizes, int n_in,
                              void* d_out, int out_size, void* d_ws, size_t ws_size,
                              hipStream_t stream)
{
  const float* query     = (const float*)d_in[0];
  const float* key_value = (const float*)d_in[1];
  const float* w_q       = (const float*)d_in[2];
  const float* w_kv      = (const float*)d_in[3];
  const float* w_out     = (const float*)d_in[4];
  const float* b_out     = (const float*)d_in[5];
  float* out = (float*)d_out;
  char* ws = (char*)d_ws;
  // layout (bytes), peak ~29.5MB:
  unsigned short* qx    = (unsigned short*)(ws + 0);         // 4MB (dead after gemm_qkv)
  unsigned short* kvx   = (unsigned short*)(ws + 4194304);   // 4MB (dead after gemm_qkv)
  unsigned short* wqT   = (unsigned short*)(ws + 8388608);
  unsigned short* wkvT  = (unsigned short*)(ws + 8519680);
  unsigned short* woutT = (unsigned short*)(ws + 8781824);
  unsigned short* Qb    = (unsigned short*)(ws + 8912896);   // 4MB (dead after attn8)
  unsigned short* Kb    = (unsigned short*)(ws + 13107200);  // 4MB
  unsigned short* VTb   = (unsigned short*)(ws + 17301504);  // 4MB
  float*          P0    = (float*)(ws + 0);                  // 8MB, aliases qx+kvx
  float*          P1    = (float*)(ws + 21495808);           // 8MB
  float*          mlb   = (float*)(ws + 29884416);           // 1MB [2 halves][m,l][16*4096]
  unsigned short* AO2   = Qb;                                // 4MB, aliases Qb (dead)

  prep<<<3072, 256, 0, stream>>>(query, key_value, w_q, w_kv, w_out,
                                 qx, kvx, wqT, wkvT, woutT);
  gemm_qkv<<<dim3(128, 12), 256, 0, stream>>>(qx, kvx, wqT, wkvT, Qb, Kb, VTb);
  attn8<<<1024, 256, 0, stream>>>(Qb, Kb, VTb, P0, P1, mlb);
  attn_merge<<<256, 256, 0, stream>>>(P0, P1, mlb, AO2);
  gemm_out<<<dim3(128, 4), 256, 0, stream>>>(AO2, woutT, out, b_out);
}